// Round 15
// baseline (15232.866 us; speedup 1.0000x reference)
//
#include <hip/hip_runtime.h>

// GRU recurrence (round 15) — column-split persistent kernel.
// Invariant found r3-r14: each CU streaming ALL weights (512KB/step) floors at
// ~6K cyc/step; register residency impossible (remat/spill). Fix: split the
// 256 h-columns across 4 sibling blocks (grid 256 = 64 row-groups x 4 col-
// quarters). Weight slice per block = 96KB w_hh + 32KB w_state -> ALL LDS-
// RESIDENT. Per-step globals: 6KB git + 2x(2KB out/6KB in) sibling exchange
// via device-scope atomics + monotonic flags (parity data slots; bounded spin).

typedef __attribute__((ext_vector_type(8))) short short8;
typedef __attribute__((ext_vector_type(4))) float f32x4;

constexpr int B_ = 1024, T_ = 128, I_ = 128, H_ = 256, OUT_ = 64;

#define DEVI __device__ __forceinline__

DEVI unsigned short f2b(float f) {
    unsigned u = __builtin_bit_cast(unsigned, f);
    u += 0x7fffu + ((u >> 16) & 1u);
    return (unsigned short)(u >> 16);
}
DEVI float b2f(unsigned short s) {
    unsigned u = ((unsigned)s) << 16;
    return __builtin_bit_cast(float, u);
}
DEVI float sigmoidf_(float x) { float e = __expf(-x); return __fdividef(1.f, 1.f + e); }
DEVI float tanhf_(float x) { float e = __expf(2.f * x); return __fdividef(e - 1.f, e + 1.f); }

DEVI f32x4 ld4(const void* p) { return *reinterpret_cast<const f32x4*>(p); }
DEVI short8 ldg8(const unsigned short* p) {
    return __builtin_bit_cast(short8, *reinterpret_cast<const uint4*>(p));
}
DEVI short8 pack8(f32x4 lo, f32x4 hi) {
    union { unsigned short s[8]; short8 v; } r;
#pragma unroll
    for (int e = 0; e < 4; ++e) { r.s[e] = f2b(lo[e]); r.s[4 + e] = f2b(hi[e]); }
    return r.v;
}
DEVI f32x4 mfma(short8 a, short8 b, f32x4 c) {
    return __builtin_amdgcn_mfma_f32_16x16x32_bf16(a, b, c, 0, 0, 0);
}
DEVI unsigned long long ldull(const unsigned short* p) {
    return *reinterpret_cast<const unsigned long long*>(p);
}
DEVI f32x4 ull2f4(unsigned long long raw) {
    f32x4 r;
#pragma unroll
    for (int e = 0; e < 4; ++e) r[e] = b2f((unsigned short)(raw >> (16 * e)));
    return r;
}
// XOR-swizzled [16][256] bf16 tile addressing
DEVI unsigned short* swz(unsigned short* base, int row, int col) {
    int byte = (row * 256 + col) * 2;
    byte ^= (row & 7) << 4;
    return (unsigned short*)((char*)base + byte);
}
DEVI const unsigned short* swzc(const unsigned short* base, int row, int col) {
    int byte = (row * 256 + col) * 2;
    byte ^= (row & 7) << 4;
    return (const unsigned short*)((const char*)base + byte);
}
// git element offset: [t][rb][cb][tile 0..11][m 0..15][16 batch]
DEVI size_t gbase(int t, int rb, int cb, int tl, int m, int kg) {
    return ((((size_t)t * 64 + rb) * 4 + cb) * 3072) + tl * 256 + m * 16 + kg * 4;
}

// ---- weight pre-conversion: f32 -> bf16 ----
__global__ void cvt_w(const float* __restrict__ src, unsigned short* __restrict__ dst, int n) {
    int i = (blockIdx.x * blockDim.x + threadIdx.x) * 8;
    if (i >= n) return;
    f32x4 lo = ld4(src + i), hi = ld4(src + i + 4);
    union { unsigned short s[8]; uint4 v; } r;
#pragma unroll
    for (int e = 0; e < 4; ++e) { r.s[e] = f2b(lo[e]); r.s[4 + e] = f2b(hi[e]); }
    *reinterpret_cast<uint4*>(dst + i) = r.v;
}

// ---- gi precompute into the tiled layout ----
__global__ __launch_bounds__(256) void gi_gemm(
    const float* __restrict__ a, const unsigned short* __restrict__ wih,
    unsigned short* __restrict__ git)
{
    const int tid = threadIdx.x;
    const int ww = tid >> 6;
    const int l = tid & 63;
    const int m = l & 15, kg = l >> 4;
    const int gr0 = blockIdx.x * 16;
    const int t = blockIdx.y;
    const int g = gr0 >> 8, c = (gr0 >> 4) & 3, cbv = (gr0 & 255) >> 6;
    const int tl = g * 4 + c;

    short8 aw[4];
#pragma unroll
    for (int kt = 0; kt < 4; ++kt)
        aw[kt] = ldg8(wih + (size_t)(gr0 + m) * I_ + kt * 32 + kg * 8);

#pragma unroll 4
    for (int bt = 0; bt < 16; ++bt) {
        const int b0 = ww * 256 + bt * 16;
        const int rb = b0 >> 4;
        const float* xr = a + (size_t)(b0 + m) * T_ * I_ + (size_t)t * I_ + kg * 8;
        short8 xb[4];
#pragma unroll
        for (int kt = 0; kt < 4; ++kt)
            xb[kt] = pack8(ld4(xr + kt * 32), ld4(xr + kt * 32 + 4));
        f32x4 acc = {0.f, 0.f, 0.f, 0.f};
#pragma unroll
        for (int kt = 0; kt < 4; ++kt) acc = mfma(xb[kt], aw[kt], acc);
        unsigned long long pk = 0;   // D: row=batch kg*4+v, col=gate gr0+m
#pragma unroll
        for (int v = 0; v < 4; ++v)
            pk |= (unsigned long long)f2b(acc[v]) << (16 * v);
        __builtin_nontemporal_store(pk, reinterpret_cast<unsigned long long*>(
            git + gbase(t, rb, cbv, tl, m, kg)));
    }
}

// ---- main persistent col-split kernel: 256 blocks (rb,cb), 768 threads ----
__global__ __launch_bounds__(768, 1) void gru_ring(
    const float* __restrict__ s0,             // [B][H] f32
    const unsigned short* __restrict__ git,   // tiled layout
    const unsigned short* __restrict__ w_hh,  // [768][256] bf16
    const unsigned short* __restrict__ w_st,  // [256][256] bf16
    const unsigned short* __restrict__ w_rw,  // [64][256] bf16
    unsigned long long* __restrict__ hn_x,    // [2][64][4][256] u64
    unsigned long long* __restrict__ s_x,     // [2][64][4][256] u64
    unsigned int* __restrict__ flag_hn,       // [64]
    unsigned int* __restrict__ flag_s,        // [64]
    float* __restrict__ out_r,                // [T][64]
    float* __restrict__ out_s)                // [B][T][H]
{
    __shared__ unsigned short whh_l[12 * 4096];  // 98304 B: 12 gate tiles
    __shared__ unsigned short wst_l[4 * 4096];   // 32768 B: 4 state tiles
    __shared__ unsigned short h16[4096];         // 8192 B: full h (bf16)
    __shared__ unsigned short hn16[4096];        // 8192 B: full h_new
    __shared__ float pre32[3][16][68];           // 13056 B: gate preacts

    const int tid = threadIdx.x;
    const int w = tid >> 6;       // wave 0..11
    const int l = tid & 63;
    const int m = l & 15;
    const int kg = l >> 4;
    const int rb = blockIdx.x & 63;
    const int cb = blockIdx.x >> 6;   // 0..3 (siblings stride 64 -> same XCD)
    const int R0 = rb * 16;

    // ---- stage weight slices + init h16 (once) ----
    if (tid < 512) {
        const int row = tid >> 5, ch = (tid & 31) * 8;
#pragma unroll
        for (int tl = 0; tl < 12; ++tl) {
            const int grow = (tl >> 2) * 256 + cb * 64 + (tl & 3) * 16 + row;
            *reinterpret_cast<uint4*>(swz(whh_l + tl * 4096, row, ch)) =
                *reinterpret_cast<const uint4*>(w_hh + (size_t)grow * 256 + ch);
        }
#pragma unroll
        for (int c = 0; c < 4; ++c) {
            const int srow = cb * 64 + c * 16 + row;
            *reinterpret_cast<uint4*>(swz(wst_l + c * 4096, row, ch)) =
                *reinterpret_cast<const uint4*>(w_st + (size_t)srow * 256 + ch);
        }
        const float* sp = s0 + (size_t)(R0 + row) * H_ + ch;
        *reinterpret_cast<uint4*>(swz(h16, row, ch)) =
            __builtin_bit_cast(uint4, pack8(ld4(sp), ld4(sp + 4)));
    }
    float hreg[4] = {0.f, 0.f, 0.f, 0.f};   // f32 carry (waves 0..3 only)
    if (w < 4) {
#pragma unroll
        for (int v = 0; v < 4; ++v)
            hreg[v] = s0[(size_t)(R0 + kg * 4 + v) * H_ + cb * 64 + w * 16 + m];
    }
    __syncthreads();

    // initial git prefetch (t=0): waves 0-7 their tile; waves 0-3 also n-tile
    unsigned long long gA = 0, gN = 0;
    if (w < 8) gA = ldull(git + gbase(0, rb, cb, w, m, kg));
    if (w < 4) gN = ldull(git + gbase(0, rb, cb, 8 + w, m, kg));

    for (int t = 0; t < T_; ++t) {
        const int p = t & 1;
        const unsigned int tgt = 4u * (t + 1);

        // ---- phase 1: all 12 waves, one gate tile each ----
        {
            f32x4 acc = (w < 8) ? ull2f4(gA) : f32x4{0.f, 0.f, 0.f, 0.f};
            short8 ha[8], wb[8];
#pragma unroll
            for (int kt = 0; kt < 8; ++kt) {
                ha[kt] = ldg8(swzc(h16, m, kt * 32 + kg * 8));
                wb[kt] = ldg8(swzc(whh_l + w * 4096, m, kt * 32 + kg * 8));
            }
#pragma unroll
            for (int kt = 0; kt < 8; ++kt) acc = mfma(ha[kt], wb[kt], acc);
            const int g = w >> 2, c = w & 3;
#pragma unroll
            for (int v = 0; v < 4; ++v) pre32[g][kg * 4 + v][c * 16 + m] = acc[v];
        }
        __syncthreads();                                    // S1

        // ---- elementwise (waves 0-3) + direct hn export ----
        if (w < 4) {
            const int jc = w * 16 + m;                      // col within my 64
            f32x4 gn = ull2f4(gN);
            unsigned long long pk = 0;
#pragma unroll
            for (int v = 0; v < 4; ++v) {
                const int b = kg * 4 + v;
                const float rg = sigmoidf_(pre32[0][b][jc]);
                const float zg = sigmoidf_(pre32[1][b][jc]);
                const float ng = tanhf_(gn[v] + rg * pre32[2][b][jc]);
                const float hv = (1.f - zg) * ng + zg * hreg[v];
                const unsigned short hb = f2b(hv);
                *swz(hn16, b, cb * 64 + jc) = hb;
                pk |= (unsigned long long)hb << (16 * v);
            }
            __hip_atomic_store(
                hn_x + (((size_t)p * 64 + rb) * 4 + cb) * 256 + jc * 4 + kg,
                pk, __ATOMIC_RELAXED, __HIP_MEMORY_SCOPE_AGENT);
        }
        __threadfence();
        __syncthreads();                                    // S2
        if (tid == 0) {
            __hip_atomic_fetch_add(flag_hn + rb, 1u, __ATOMIC_RELEASE,
                                   __HIP_MEMORY_SCOPE_AGENT);
            int guard = 0;
            while (__hip_atomic_load(flag_hn + rb, __ATOMIC_ACQUIRE,
                                     __HIP_MEMORY_SCOPE_AGENT) < tgt &&
                   ++guard < (1 << 22)) __builtin_amdgcn_s_sleep(2);
        }
        __syncthreads();                                    // S3
        {   // import foreign hn: 3 siblings x 256 u64
            const int s = tid >> 8, i = tid & 255;
            const int cbf = s + (s >= cb);
            const int col = i >> 2, kq = i & 3;
            unsigned long long v64 = __hip_atomic_load(
                hn_x + (((size_t)p * 64 + rb) * 4 + cbf) * 256 + col * 4 + kq,
                __ATOMIC_RELAXED, __HIP_MEMORY_SCOPE_AGENT);
#pragma unroll
            for (int vv = 0; vv < 4; ++vv)
                *swz(hn16, kq * 4 + vv, cbf * 64 + col) =
                    (unsigned short)(v64 >> (16 * vv));
        }
        __syncthreads();                                    // S4

        // ---- phase 2 (waves 0-3) + r_t (wave 4, rb==0) + git prefetch ----
        if (w < 4) {
            short8 na[8], wsb[8];
#pragma unroll
            for (int kt = 0; kt < 8; ++kt) {
                na[kt]  = ldg8(swzc(hn16, m, kt * 32 + kg * 8));
                wsb[kt] = ldg8(swzc(wst_l + w * 4096, m, kt * 32 + kg * 8));
            }
            f32x4 a2 = {0.f, 0.f, 0.f, 0.f};
#pragma unroll
            for (int kt = 0; kt < 8; ++kt) a2 = mfma(na[kt], wsb[kt], a2);
            const int jc = w * 16 + m;
            unsigned long long pk = 0;
#pragma unroll
            for (int v = 0; v < 4; ++v) {
                const int b = kg * 4 + v;
                const float sv = sigmoidf_(a2[v]);
                hreg[v] = sv;
                const unsigned short sb = f2b(sv);
                *swz(h16, b, cb * 64 + jc) = sb;
                out_s[((size_t)(R0 + b) * T_ + t) * H_ + cb * 64 + jc] = sv;
                pk |= (unsigned long long)sb << (16 * v);
            }
            __hip_atomic_store(
                s_x + (((size_t)p * 64 + rb) * 4 + cb) * 256 + jc * 4 + kg,
                pk, __ATOMIC_RELAXED, __HIP_MEMORY_SCOPE_AGENT);
        } else if (w == 4 && rb == 0) {
            short8 na[8];
#pragma unroll
            for (int kt = 0; kt < 8; ++kt)
                na[kt] = ldg8(swzc(hn16, m, kt * 32 + kg * 8));
            f32x4 a2 = {0.f, 0.f, 0.f, 0.f};
#pragma unroll
            for (int kt = 0; kt < 8; ++kt)
                a2 = mfma(na[kt],
                          ldg8(w_rw + (size_t)(cb * 16 + m) * 256 + kt * 32 + kg * 8),
                          a2);
            if (kg == 0) out_r[t * OUT_ + cb * 16 + m] = sigmoidf_(a2[0]);
        }
        {   // git prefetch for t+1
            const int tn = (t + 1 < T_) ? t + 1 : t;
            if (w < 8) gA = ldull(git + gbase(tn, rb, cb, w, m, kg));
            if (w < 4) gN = ldull(git + gbase(tn, rb, cb, 8 + w, m, kg));
        }
        __threadfence();
        __syncthreads();                                    // S5
        if (tid == 0) {
            __hip_atomic_fetch_add(flag_s + rb, 1u, __ATOMIC_RELEASE,
                                   __HIP_MEMORY_SCOPE_AGENT);
            int guard = 0;
            while (__hip_atomic_load(flag_s + rb, __ATOMIC_ACQUIRE,
                                     __HIP_MEMORY_SCOPE_AGENT) < tgt &&
                   ++guard < (1 << 22)) __builtin_amdgcn_s_sleep(2);
        }
        __syncthreads();                                    // S6
        {   // import foreign s -> h16
            const int s = tid >> 8, i = tid & 255;
            const int cbf = s + (s >= cb);
            const int col = i >> 2, kq = i & 3;
            unsigned long long v64 = __hip_atomic_load(
                s_x + (((size_t)p * 64 + rb) * 4 + cbf) * 256 + col * 4 + kq,
                __ATOMIC_RELAXED, __HIP_MEMORY_SCOPE_AGENT);
#pragma unroll
            for (int vv = 0; vv < 4; ++vv)
                *swz(h16, kq * 4 + vv, cbf * 64 + col) =
                    (unsigned short)(v64 >> (16 * vv));
        }
        __syncthreads();                                    // S7
    }
}

// ---- fallback (ws too small): r13-style streaming kernel, 64 blocks ----
__global__ __launch_bounds__(512, 1) void gru_fallback(
    const float* __restrict__ s0, const float* __restrict__ a,
    const unsigned short* __restrict__ w_ih, const unsigned short* __restrict__ w_hh,
    const unsigned short* __restrict__ w_rw, const unsigned short* __restrict__ w_st,
    float* __restrict__ out_r, float* __restrict__ out_s)
{
    __shared__ unsigned short wst_l[H_ * 256];
    __shared__ unsigned short h16a[16 * 256];
    __shared__ unsigned short hn16a[16 * 256];
    const int tid = threadIdx.x;
    const int w = tid >> 6, l = tid & 63, m = l & 15, kg = l >> 4;
    const int R0 = blockIdx.x * 16;
    const int g0 = (2 * w + 0) * 16 + m, g1 = (2 * w + 1) * 16 + m;
#pragma unroll
    for (int i = 0; i < 16; ++i) {
        const int idx = (tid + i * 512) * 8;
        *reinterpret_cast<uint4*>(swz(wst_l, idx >> 8, idx & 255)) =
            *reinterpret_cast<const uint4*>(w_st + idx);
    }
    {
        const int pr = tid >> 5, pc = (tid & 31) * 8;
        const float* sp = &s0[(size_t)(R0 + pr) * H_ + pc];
        *reinterpret_cast<uint4*>(swz(h16a, pr, pc)) =
            __builtin_bit_cast(uint4, pack8(ld4(sp), ld4(sp + 4)));
    }
    float hreg0[4], hreg1[4];
#pragma unroll
    for (int v = 0; v < 4; ++v) {
        hreg0[v] = s0[(size_t)(R0 + kg * 4 + v) * H_ + g0];
        hreg1[v] = s0[(size_t)(R0 + kg * 4 + v) * H_ + g1];
    }
    __syncthreads();
    for (int t = 0; t < T_; ++t) {
        short8 ha[8];
#pragma unroll
        for (int kt = 0; kt < 8; ++kt) ha[kt] = ldg8(swzc(h16a, m, kt * 32 + kg * 8));
        f32x4 ar0 = {0,0,0,0}, az0 = {0,0,0,0}, ani0 = {0,0,0,0};
        f32x4 ar1 = {0,0,0,0}, az1 = {0,0,0,0}, ani1 = {0,0,0,0};
        short8 xa[4];
        const float* xr = a + ((size_t)(R0 + m) * T_ + t) * I_ + kg * 8;
#pragma unroll
        for (int kt = 0; kt < 4; ++kt)
            xa[kt] = pack8(ld4(xr + kt * 32), ld4(xr + kt * 32 + 4));
        const unsigned short* p0 = w_ih + (size_t)g0 * I_ + kg * 8;
        const unsigned short* p1 = w_ih + (size_t)g1 * I_ + kg * 8;
#pragma unroll
        for (int kt = 0; kt < 4; ++kt) {
            ar0  = mfma(xa[kt], ldg8(p0 + kt * 32),            ar0);
            az0  = mfma(xa[kt], ldg8(p0 + 256 * I_ + kt * 32), az0);
            ani0 = mfma(xa[kt], ldg8(p0 + 512 * I_ + kt * 32), ani0);
            ar1  = mfma(xa[kt], ldg8(p1 + kt * 32),            ar1);
            az1  = mfma(xa[kt], ldg8(p1 + 256 * I_ + kt * 32), az1);
            ani1 = mfma(xa[kt], ldg8(p1 + 512 * I_ + kt * 32), ani1);
        }
        f32x4 anh0 = {0,0,0,0}, anh1 = {0,0,0,0};
        const unsigned short* q0 = w_hh + (size_t)g0 * H_ + kg * 8;
        const unsigned short* q1 = w_hh + (size_t)g1 * H_ + kg * 8;
#pragma unroll
        for (int kt = 0; kt < 8; ++kt) {
            ar0  = mfma(ha[kt], ldg8(q0 + kt * 32),            ar0);
            az0  = mfma(ha[kt], ldg8(q0 + 256 * H_ + kt * 32), az0);
            anh0 = mfma(ha[kt], ldg8(q0 + 512 * H_ + kt * 32), anh0);
            ar1  = mfma(ha[kt], ldg8(q1 + kt * 32),            ar1);
            az1  = mfma(ha[kt], ldg8(q1 + 256 * H_ + kt * 32), az1);
            anh1 = mfma(ha[kt], ldg8(q1 + 512 * H_ + kt * 32), anh1);
        }
#pragma unroll
        for (int v = 0; v < 4; ++v) {
            const int row = kg * 4 + v;
            float rg = sigmoidf_(ar0[v]), zg = sigmoidf_(az0[v]);
            float ng = tanhf_(ani0[v] + rg * anh0[v]);
            *swz(hn16a, row, g0) = f2b((1.f - zg) * ng + zg * hreg0[v]);
            rg = sigmoidf_(ar1[v]); zg = sigmoidf_(az1[v]);
            ng = tanhf_(ani1[v] + rg * anh1[v]);
            *swz(hn16a, row, g1) = f2b((1.f - zg) * ng + zg * hreg1[v]);
        }
        __syncthreads();
        short8 na[8];
#pragma unroll
        for (int kt = 0; kt < 8; ++kt) na[kt] = ldg8(swzc(hn16a, m, kt * 32 + kg * 8));
        f32x4 sa0 = {0,0,0,0}, sa1 = {0,0,0,0};
#pragma unroll
        for (int kt = 0; kt < 8; ++kt) {
            sa0 = mfma(na[kt], ldg8(swzc(wst_l, g0, kt * 32 + kg * 8)), sa0);
            sa1 = mfma(na[kt], ldg8(swzc(wst_l, g1, kt * 32 + kg * 8)), sa1);
        }
#pragma unroll
        for (int v = 0; v < 4; ++v) {
            const int row = kg * 4 + v;
            const float u0 = sigmoidf_(sa0[v]), u1 = sigmoidf_(sa1[v]);
            hreg0[v] = u0; hreg1[v] = u1;
            *swz(h16a, row, g0) = f2b(u0);
            *swz(h16a, row, g1) = f2b(u1);
            float* dst = &out_s[((size_t)(R0 + row) * T_ + t) * H_];
            dst[g0] = u0; dst[g1] = u1;
        }
        if (blockIdx.x == 0 && w < 4) {
            const int o = w * 16 + m;
            f32x4 accr = {0,0,0,0};
            const unsigned short* pw = w_rw + (size_t)o * H_ + kg * 8;
#pragma unroll
            for (int kt = 0; kt < 8; ++kt) accr = mfma(na[kt], ldg8(pw + kt * 32), accr);
            if (kg == 0) out_r[t * OUT_ + o] = sigmoidf_(accr[0]);
        }
        __syncthreads();
    }
}

extern "C" void kernel_launch(void* const* d_in, const int* in_sizes, int n_in,
                              void* d_out, int out_size, void* d_ws, size_t ws_size,
                              hipStream_t stream) {
    const float* s0  = (const float*)d_in[0];
    const float* a   = (const float*)d_in[1];
    const float* wih = (const float*)d_in[2];
    const float* whh = (const float*)d_in[3];
    const float* wrw = (const float*)d_in[4];
    const float* wst = (const float*)d_in[5];

    const size_t git_e  = (size_t)T_ * 64 * 4 * 3072;     // 100,663,296 u16
    const size_t wtot_e = 98304 + 196608 + 16384 + 65536; // 376,832 u16
    const size_t xch_e  = 2 * 64 * 4 * 1024;              // 524,288 u16 each
    const size_t need_b = (git_e + wtot_e + 2 * xch_e + 256) * 2;
    const bool ring = ws_size >= need_b;

    unsigned short* ws16  = (unsigned short*)d_ws;
    unsigned short* git   = ws16;
    unsigned short* wih16 = ws16 + (ring ? git_e : 0);
    unsigned short* whh16 = wih16 + 98304;
    unsigned short* wrw16 = whh16 + 196608;
    unsigned short* wst16 = wrw16 + 16384;

    cvt_w<<<98304  / (256 * 8), 256, 0, stream>>>(wih, wih16, 98304);
    cvt_w<<<196608 / (256 * 8), 256, 0, stream>>>(whh, whh16, 196608);
    cvt_w<<<16384  / (256 * 8), 256, 0, stream>>>(wrw, wrw16, 16384);
    cvt_w<<<65536  / (256 * 8), 256, 0, stream>>>(wst, wst16, 65536);

    float* out = (float*)d_out;
    if (ring) {
        unsigned long long* hn_x = (unsigned long long*)(wst16 + 65536);
        unsigned long long* s_x  = hn_x + xch_e / 4;      // xch_e u16 = /4 u64
        unsigned int* flag_hn    = (unsigned int*)(s_x + xch_e / 4);
        unsigned int* flag_s     = flag_hn + 64;
        hipMemsetAsync(flag_hn, 0, 512, stream);
        gi_gemm<<<dim3(48, T_), 256, 0, stream>>>(a, wih16, git);
        gru_ring<<<256, 768, 0, stream>>>(s0, git, whh16, wst16, wrw16,
                                          hn_x, s_x, flag_hn, flag_s,
                                          out, out + (size_t)T_ * OUT_);
    } else {
        gru_fallback<<<64, 512, 0, stream>>>(s0, a, wih16, whh16, wrw16, wst16,
                                             out, out + (size_t)T_ * OUT_);
    }
}

// Round 16
// 1364.368 us; speedup vs baseline: 11.1648x; 11.1648x over previous
//
#include <hip/hip_runtime.h>

// GRU recurrence (round 16).
// r15 ring: cross-block sync = 118us/step -> dead. Revert to r11 champion and
// apply the one untried lever: 16 waves (1024 thr), ONE 16-col tile per wave
// -> per-wave w_hh chain halves (24 frags), 4 waves/SIMD latency overlap.
// Keep: w_state LDS-resident, gi-precompute, r14 git tiled layout + nt +
// 1-step-ahead prefetch, compiler-scheduled w_hh loads (r11 lesson: no pins),
// out_s nt stores. gi_gemm restructured to read x once (was 48x).

typedef __attribute__((ext_vector_type(8))) short short8;
typedef __attribute__((ext_vector_type(4))) float f32x4;

constexpr int B_ = 1024, T_ = 128, I_ = 128, H_ = 256, OUT_ = 64;
constexpr int ROWS = 16;
constexpr int NBLK = B_ / ROWS;  // 64

#define DEVI __device__ __forceinline__

DEVI unsigned short f2b(float f) {
    unsigned u = __builtin_bit_cast(unsigned, f);
    u += 0x7fffu + ((u >> 16) & 1u);
    return (unsigned short)(u >> 16);
}
DEVI float b2f(unsigned short s) {
    unsigned u = ((unsigned)s) << 16;
    return __builtin_bit_cast(float, u);
}
DEVI float sigmoidf_(float x) { float e = __expf(-x); return __fdividef(1.f, 1.f + e); }
DEVI float tanhf_(float x) { float e = __expf(2.f * x); return __fdividef(e - 1.f, e + 1.f); }

DEVI f32x4 ld4(const void* p) { return *reinterpret_cast<const f32x4*>(p); }
DEVI short8 ldg8(const unsigned short* p) {
    return __builtin_bit_cast(short8, *reinterpret_cast<const uint4*>(p));
}
DEVI short8 pack8(f32x4 lo, f32x4 hi) {
    union { unsigned short s[8]; short8 v; } r;
#pragma unroll
    for (int e = 0; e < 4; ++e) { r.s[e] = f2b(lo[e]); r.s[4 + e] = f2b(hi[e]); }
    return r.v;
}
DEVI f32x4 mfma(short8 a, short8 b, f32x4 c) {
    return __builtin_amdgcn_mfma_f32_16x16x32_bf16(a, b, c, 0, 0, 0);
}
DEVI f32x4 ull2f4(unsigned long long raw) {
    f32x4 r;
#pragma unroll
    for (int e = 0; e < 4; ++e) r[e] = b2f((unsigned short)(raw >> (16 * e)));
    return r;
}
// XOR-swizzled [*][256] bf16 tile: byte ^= (row&7)<<4
DEVI unsigned short* swz(unsigned short* base, int row, int col) {
    int byte = (row * 256 + col) * 2;
    byte ^= (row & 7) << 4;
    return (unsigned short*)((char*)base + byte);
}
DEVI const unsigned short* swzc(const unsigned short* base, int row, int col) {
    int byte = (row * 256 + col) * 2;
    byte ^= (row & 7) << 4;
    return (const unsigned short*)((const char*)base + byte);
}

// ---- weight pre-conversion: f32 -> bf16 ----
__global__ void cvt_w(const float* __restrict__ src, unsigned short* __restrict__ dst, int n) {
    int i = (blockIdx.x * blockDim.x + threadIdx.x) * 8;
    if (i >= n) return;
    f32x4 lo = ld4(src + i), hi = ld4(src + i + 4);
    union { unsigned short s[8]; uint4 v; } r;
#pragma unroll
    for (int e = 0; e < 4; ++e) { r.s[e] = f2b(lo[e]); r.s[4 + e] = f2b(hi[e]); }
    *reinterpret_cast<uint4*>(dst + i) = r.v;
}

// ---- gi precompute: git[((t*64 + rb)*768 + gate)*16 + bi], x read ONCE ----
// grid (16, 128): block = (64-batch-row chunk, t); 4 waves, one 16-row group
// each; loop over all 48 gate tiles reusing the x fragments.
__global__ __launch_bounds__(256) void gi_gemm(
    const float* __restrict__ a, const unsigned short* __restrict__ wih,
    unsigned short* __restrict__ git)
{
    const int tid = threadIdx.x;
    const int ww = tid >> 6;
    const int l = tid & 63;
    const int m = l & 15, kg = l >> 4;
    const int b0 = blockIdx.x * 64 + ww * 16;
    const int rb = b0 >> 4;
    const int t = blockIdx.y;

    short8 xb[4];
    {
        const float* xr = a + (size_t)(b0 + m) * T_ * I_ + (size_t)t * I_ + kg * 8;
#pragma unroll
        for (int kt = 0; kt < 4; ++kt)
            xb[kt] = pack8(ld4(xr + kt * 32), ld4(xr + kt * 32 + 4));
    }
#pragma unroll 4
    for (int tl = 0; tl < 48; ++tl) {
        const int gr0 = tl * 16;
        short8 aw[4];
#pragma unroll
        for (int kt = 0; kt < 4; ++kt)
            aw[kt] = ldg8(wih + (size_t)(gr0 + m) * I_ + kt * 32 + kg * 8);
        f32x4 acc = {0.f, 0.f, 0.f, 0.f};
#pragma unroll
        for (int kt = 0; kt < 4; ++kt) acc = mfma(xb[kt], aw[kt], acc);
        // D: row = batch (kg*4+v), col = gate (gr0+m) -> packed 8B nt store
        unsigned long long pk = 0;
#pragma unroll
        for (int v = 0; v < 4; ++v)
            pk |= (unsigned long long)f2b(acc[v]) << (16 * v);
        __builtin_nontemporal_store(pk, reinterpret_cast<unsigned long long*>(
            git + (((size_t)t * 64 + rb) * 768 + gr0 + m) * 16 + kg * 4));
    }
}

// ---- main kernel: 64 blocks x 1024 threads (16 waves, 1 col-tile each) ----
__global__ __launch_bounds__(1024, 1) void gru_fused16(
    const float* __restrict__ s0,             // [B][H] f32
    const unsigned short* __restrict__ git,   // [T][64][768][16] bf16
    const unsigned short* __restrict__ w_hh,  // [3H][H] bf16
    const unsigned short* __restrict__ w_rw,  // [OUT][H] bf16
    const unsigned short* __restrict__ w_st,  // [H][H] bf16
    float* __restrict__ out_r,                // [T][OUT] f32
    float* __restrict__ out_s)                // [B][T][H] f32
{
    __shared__ unsigned short wst_l[H_ * 256];  // 131072 B, swizzled
    __shared__ unsigned short h16[ROWS * 256];  // 8192 B
    __shared__ unsigned short hn16[ROWS * 256]; // 8192 B   total 147456

    const int tid = threadIdx.x;
    const int w = tid >> 6;       // wave 0..15 -> one 16-col tile
    const int l = tid & 63;
    const int m = l & 15;
    const int kg = l >> 4;
    const int R0 = blockIdx.x * ROWS;
    const int gcol = w * 16 + m;  // this wave's gate/state column

    // stage w_state into LDS, swizzled (8192 uint4; 8 per thread)
#pragma unroll
    for (int i = 0; i < 8; ++i) {
        const int idx = (tid + i * 1024) * 8;
        *reinterpret_cast<uint4*>(swz(wst_l, idx >> 8, idx & 255)) =
            *reinterpret_cast<const uint4*>(w_st + idx);
    }
    // init h16
    if (tid < 512) {
        const int pr = tid >> 5, pc = (tid & 31) * 8;
        const float* sp = &s0[(size_t)(R0 + pr) * H_ + pc];
        *reinterpret_cast<uint4*>(swz(h16, pr, pc)) =
            __builtin_bit_cast(uint4, pack8(ld4(sp), ld4(sp + 4)));
    }
    float hreg[4];
#pragma unroll
    for (int v = 0; v < 4; ++v)
        hreg[v] = s0[(size_t)(R0 + kg * 4 + v) * H_ + gcol];
    __syncthreads();

    const unsigned short* pwh = w_hh + (size_t)gcol * H_ + kg * 8;

    // git prefetch (t=0): 3 u64 per wave (r, z, n-input slices of its tile)
    unsigned long long gr0_, gr1_, gr2_;
    {
        const unsigned short* gt = git + (size_t)blockIdx.x * 768 * 16;
        gr0_ = __builtin_nontemporal_load(
            reinterpret_cast<const unsigned long long*>(gt + (gcol)       * 16 + kg * 4));
        gr1_ = __builtin_nontemporal_load(
            reinterpret_cast<const unsigned long long*>(gt + (gcol + 256) * 16 + kg * 4));
        gr2_ = __builtin_nontemporal_load(
            reinterpret_cast<const unsigned long long*>(gt + (gcol + 512) * 16 + kg * 4));
    }

    for (int t = 0; t < T_; ++t) {
        // ---- phase 1: gate GEMM for this wave's tile ----
        f32x4 ar  = ull2f4(gr0_);
        f32x4 az  = ull2f4(gr1_);
        f32x4 ani = ull2f4(gr2_);
        f32x4 anh = {0.f, 0.f, 0.f, 0.f};

        short8 ha[8];
#pragma unroll
        for (int kt = 0; kt < 8; ++kt)
            ha[kt] = ldg8(swzc(h16, m, kt * 32 + kg * 8));
        // w_hh streamed, compiler-scheduled (r11 lesson: no manual pins)
#pragma unroll
        for (int kt = 0; kt < 8; ++kt)
            ar  = mfma(ha[kt], ldg8(pwh + kt * 32),            ar);
#pragma unroll
        for (int kt = 0; kt < 8; ++kt)
            az  = mfma(ha[kt], ldg8(pwh + 256 * H_ + kt * 32), az);
#pragma unroll
        for (int kt = 0; kt < 8; ++kt)
            anh = mfma(ha[kt], ldg8(pwh + 512 * H_ + kt * 32), anh);

        // gates -> h_new (D: row = kg*4+v, col = m -> gcol)
#pragma unroll
        for (int v = 0; v < 4; ++v) {
            const int row = kg * 4 + v;
            const float rg = sigmoidf_(ar[v]);
            const float zg = sigmoidf_(az[v]);
            const float ng = tanhf_(ani[v] + rg * anh[v]);
            *swz(hn16, row, gcol) = f2b((1.f - zg) * ng + zg * hreg[v]);
        }
        __syncthreads();                      // S1: hn16 ready

        // ---- prefetch git(t+1): a full phase ahead of use ----
        {
            const int tn = (t + 1 < T_) ? t + 1 : t;
            const unsigned short* gt = git + ((size_t)tn * 64 + blockIdx.x) * 768 * 16;
            gr0_ = __builtin_nontemporal_load(
                reinterpret_cast<const unsigned long long*>(gt + (gcol)       * 16 + kg * 4));
            gr1_ = __builtin_nontemporal_load(
                reinterpret_cast<const unsigned long long*>(gt + (gcol + 256) * 16 + kg * 4));
            gr2_ = __builtin_nontemporal_load(
                reinterpret_cast<const unsigned long long*>(gt + (gcol + 512) * 16 + kg * 4));
        }

        // ---- phase 2: s_next = sig(h_new @ w_state^T), LDS operands ----
        short8 na[8];
#pragma unroll
        for (int kt = 0; kt < 8; ++kt)
            na[kt] = ldg8(swzc(hn16, m, kt * 32 + kg * 8));
        f32x4 sa = {0.f, 0.f, 0.f, 0.f};
#pragma unroll
        for (int kt = 0; kt < 8; ++kt)
            sa = mfma(na[kt], ldg8(swzc(wst_l, gcol, kt * 32 + kg * 8)), sa);
#pragma unroll
        for (int v = 0; v < 4; ++v) {
            const int row = kg * 4 + v;
            const float sv = sigmoidf_(sa[v]);
            hreg[v] = sv;
            *swz(h16, row, gcol) = f2b(sv);
            __builtin_nontemporal_store(
                sv, &out_s[((size_t)(R0 + row) * T_ + t) * H_ + gcol]);
        }
        if (blockIdx.x == 0 && w < 4) {       // r_t = sig(h_new[0] @ w_reward^T)
            const int o = w * 16 + m;
            f32x4 accr = {0.f, 0.f, 0.f, 0.f};
            const unsigned short* p = w_rw + (size_t)o * H_ + kg * 8;
#pragma unroll
            for (int kt = 0; kt < 8; ++kt)
                accr = mfma(na[kt], ldg8(p + kt * 32), accr);
            if (kg == 0)
                out_r[t * OUT_ + o] = sigmoidf_(accr[0]);
        }
        __syncthreads();                      // S2: h16 ready for t+1
    }
}

// ---- fallback (ws too small): r11-style streaming kernel, 64 blocks ----
__global__ __launch_bounds__(512, 1) void gru_fallback(
    const float* __restrict__ s0, const float* __restrict__ a,
    const unsigned short* __restrict__ w_ih, const unsigned short* __restrict__ w_hh,
    const unsigned short* __restrict__ w_rw, const unsigned short* __restrict__ w_st,
    float* __restrict__ out_r, float* __restrict__ out_s)
{
    __shared__ unsigned short wst_l[H_ * 256];
    __shared__ unsigned short h16a[16 * 256];
    __shared__ unsigned short hn16a[16 * 256];
    const int tid = threadIdx.x;
    const int w = tid >> 6, l = tid & 63, m = l & 15, kg = l >> 4;
    const int R0 = blockIdx.x * 16;
    const int g0 = (2 * w + 0) * 16 + m, g1 = (2 * w + 1) * 16 + m;
#pragma unroll
    for (int i = 0; i < 16; ++i) {
        const int idx = (tid + i * 512) * 8;
        *reinterpret_cast<uint4*>(swz(wst_l, idx >> 8, idx & 255)) =
            *reinterpret_cast<const uint4*>(w_st + idx);
    }
    {
        const int pr = tid >> 5, pc = (tid & 31) * 8;
        const float* sp = &s0[(size_t)(R0 + pr) * H_ + pc];
        *reinterpret_cast<uint4*>(swz(h16a, pr, pc)) =
            __builtin_bit_cast(uint4, pack8(ld4(sp), ld4(sp + 4)));
    }
    float hreg0[4], hreg1[4];
#pragma unroll
    for (int v = 0; v < 4; ++v) {
        hreg0[v] = s0[(size_t)(R0 + kg * 4 + v) * H_ + g0];
        hreg1[v] = s0[(size_t)(R0 + kg * 4 + v) * H_ + g1];
    }
    __syncthreads();
    for (int t = 0; t < T_; ++t) {
        short8 ha[8];
#pragma unroll
        for (int kt = 0; kt < 8; ++kt) ha[kt] = ldg8(swzc(h16a, m, kt * 32 + kg * 8));
        f32x4 ar0 = {0,0,0,0}, az0 = {0,0,0,0}, ani0 = {0,0,0,0};
        f32x4 ar1 = {0,0,0,0}, az1 = {0,0,0,0}, ani1 = {0,0,0,0};
        short8 xa[4];
        const float* xr = a + ((size_t)(R0 + m) * T_ + t) * I_ + kg * 8;
#pragma unroll
        for (int kt = 0; kt < 4; ++kt)
            xa[kt] = pack8(ld4(xr + kt * 32), ld4(xr + kt * 32 + 4));
        const unsigned short* p0 = w_ih + (size_t)g0 * I_ + kg * 8;
        const unsigned short* p1 = w_ih + (size_t)g1 * I_ + kg * 8;
#pragma unroll
        for (int kt = 0; kt < 4; ++kt) {
            ar0  = mfma(xa[kt], ldg8(p0 + kt * 32),            ar0);
            az0  = mfma(xa[kt], ldg8(p0 + 256 * I_ + kt * 32), az0);
            ani0 = mfma(xa[kt], ldg8(p0 + 512 * I_ + kt * 32), ani0);
            ar1  = mfma(xa[kt], ldg8(p1 + kt * 32),            ar1);
            az1  = mfma(xa[kt], ldg8(p1 + 256 * I_ + kt * 32), az1);
            ani1 = mfma(xa[kt], ldg8(p1 + 512 * I_ + kt * 32), ani1);
        }
        f32x4 anh0 = {0,0,0,0}, anh1 = {0,0,0,0};
        const unsigned short* q0 = w_hh + (size_t)g0 * H_ + kg * 8;
        const unsigned short* q1 = w_hh + (size_t)g1 * H_ + kg * 8;
#pragma unroll
        for (int kt = 0; kt < 8; ++kt) {
            ar0  = mfma(ha[kt], ldg8(q0 + kt * 32),            ar0);
            az0  = mfma(ha[kt], ldg8(q0 + 256 * H_ + kt * 32), az0);
            anh0 = mfma(ha[kt], ldg8(q0 + 512 * H_ + kt * 32), anh0);
            ar1  = mfma(ha[kt], ldg8(q1 + kt * 32),            ar1);
            az1  = mfma(ha[kt], ldg8(q1 + 256 * H_ + kt * 32), az1);
            anh1 = mfma(ha[kt], ldg8(q1 + 512 * H_ + kt * 32), anh1);
        }
#pragma unroll
        for (int v = 0; v < 4; ++v) {
            const int row = kg * 4 + v;
            float rg = sigmoidf_(ar0[v]), zg = sigmoidf_(az0[v]);
            float ng = tanhf_(ani0[v] + rg * anh0[v]);
            *swz(hn16a, row, g0) = f2b((1.f - zg) * ng + zg * hreg0[v]);
            rg = sigmoidf_(ar1[v]); zg = sigmoidf_(az1[v]);
            ng = tanhf_(ani1[v] + rg * anh1[v]);
            *swz(hn16a, row, g1) = f2b((1.f - zg) * ng + zg * hreg1[v]);
        }
        __syncthreads();
        short8 na[8];
#pragma unroll
        for (int kt = 0; kt < 8; ++kt) na[kt] = ldg8(swzc(hn16a, m, kt * 32 + kg * 8));
        f32x4 sa0 = {0,0,0,0}, sa1 = {0,0,0,0};
#pragma unroll
        for (int kt = 0; kt < 8; ++kt) {
            sa0 = mfma(na[kt], ldg8(swzc(wst_l, g0, kt * 32 + kg * 8)), sa0);
            sa1 = mfma(na[kt], ldg8(swzc(wst_l, g1, kt * 32 + kg * 8)), sa1);
        }
#pragma unroll
        for (int v = 0; v < 4; ++v) {
            const int row = kg * 4 + v;
            const float u0 = sigmoidf_(sa0[v]), u1 = sigmoidf_(sa1[v]);
            hreg0[v] = u0; hreg1[v] = u1;
            *swz(h16a, row, g0) = f2b(u0);
            *swz(h16a, row, g1) = f2b(u1);
            float* dst = &out_s[((size_t)(R0 + row) * T_ + t) * H_];
            dst[g0] = u0; dst[g1] = u1;
        }
        if (blockIdx.x == 0 && w < 4) {
            const int o = w * 16 + m;
            f32x4 accr = {0,0,0,0};
            const unsigned short* pw = w_rw + (size_t)o * H_ + kg * 8;
#pragma unroll
            for (int kt = 0; kt < 8; ++kt) accr = mfma(na[kt], ldg8(pw + kt * 32), accr);
            if (kg == 0) out_r[t * OUT_ + o] = sigmoidf_(accr[0]);
        }
        __syncthreads();
    }
}

extern "C" void kernel_launch(void* const* d_in, const int* in_sizes, int n_in,
                              void* d_out, int out_size, void* d_ws, size_t ws_size,
                              hipStream_t stream) {
    const float* s0  = (const float*)d_in[0];
    const float* a   = (const float*)d_in[1];
    const float* wih = (const float*)d_in[2];
    const float* whh = (const float*)d_in[3];
    const float* wrw = (const float*)d_in[4];
    const float* wst = (const float*)d_in[5];

    const size_t git_e  = (size_t)T_ * 64 * 768 * 16;     // 100,663,296 u16
    const size_t wtot_e = 98304 + 196608 + 16384 + 65536; // 376,832 u16
    const bool pregi = ws_size >= (git_e + wtot_e) * 2;

    unsigned short* ws16  = (unsigned short*)d_ws;
    unsigned short* git   = ws16;
    unsigned short* wih16 = ws16 + (pregi ? git_e : 0);
    unsigned short* whh16 = wih16 + 98304;
    unsigned short* wrw16 = whh16 + 196608;
    unsigned short* wst16 = wrw16 + 16384;

    cvt_w<<<98304  / (256 * 8), 256, 0, stream>>>(wih, wih16, 98304);
    cvt_w<<<196608 / (256 * 8), 256, 0, stream>>>(whh, whh16, 196608);
    cvt_w<<<16384  / (256 * 8), 256, 0, stream>>>(wrw, wrw16, 16384);
    cvt_w<<<65536  / (256 * 8), 256, 0, stream>>>(wst, wst16, 65536);

    float* out = (float*)d_out;
    if (pregi) {
        gi_gemm<<<dim3(16, T_), 256, 0, stream>>>(a, wih16, git);
        gru_fused16<<<NBLK, 1024, 0, stream>>>(s0, git, whh16, wrw16, wst16,
                                               out, out + (size_t)T_ * OUT_);
    } else {
        gru_fallback<<<64, 512, 0, stream>>>(s0, a, wih16, whh16, wrw16, wst16,
                                             out, out + (size_t)T_ * OUT_);
    }
}

// Round 17
// 1299.834 us; speedup vs baseline: 11.7191x; 1.0496x over previous
//
#include <hip/hip_runtime.h>

// GRU recurrence (round 17).
// r16 analysis: per-step cost = w_hh stream floor (~6K cyc) + latency + 1.5K
// bank-conflict cyc (scalar u16 column writes) + heavy activation VALU.
// This round: OPERAND-SWAPPED MFMAs -> D = (gate, batch) per lane:
//   - hn16/h16 writes: 4x scalar u16 -> one ds_write_b64 (packed via
//     v_cvt_pk_bf16_f32)
//   - out_s: 4 scattered f32 -> one float4 nt store
//   - git: transposed layout, one u64/lane
//   - exp2-based sigmoid/tanh (v_exp_f32 + v_rcp_f32)
//   - launch_bounds(1024,4): explicit 128-VGPR allowance
// Carry hreg stays lane-local (phase-2 writer lane == phase-1 reader lane).

typedef __attribute__((ext_vector_type(8))) short short8;
typedef __attribute__((ext_vector_type(4))) float f32x4;

constexpr int B_ = 1024, T_ = 128, I_ = 128, H_ = 256, OUT_ = 64;
constexpr int ROWS = 16;
constexpr int NBLK = B_ / ROWS;  // 64

#define DEVI __device__ __forceinline__

DEVI unsigned short f2b(float f) {
    unsigned u = __builtin_bit_cast(unsigned, f);
    u += 0x7fffu + ((u >> 16) & 1u);
    return (unsigned short)(u >> 16);
}
DEVI float b2f(unsigned short s) {
    unsigned u = ((unsigned)s) << 16;
    return __builtin_bit_cast(float, u);
}
DEVI unsigned cvtpk(float lo, float hi) {   // 2 f32 -> packed 2 bf16 (1 VALU op)
    unsigned r;
    asm("v_cvt_pk_bf16_f32 %0, %1, %2" : "=v"(r) : "v"(lo), "v"(hi));
    return r;
}
DEVI float sigmoid2_(float x) {             // 1/(1+2^(-x*log2e))
    float e = __builtin_amdgcn_exp2f(-1.44269504f * x);
    return __builtin_amdgcn_rcpf(1.f + e);
}
DEVI float tanh2_(float x) {                // (e2-1)/(e2+1), e2 = 2^(2x*log2e)
    float e = __builtin_amdgcn_exp2f(2.88539009f * x);
    return (e - 1.f) * __builtin_amdgcn_rcpf(e + 1.f);
}

DEVI f32x4 ld4(const void* p) { return *reinterpret_cast<const f32x4*>(p); }
DEVI short8 ldg8(const unsigned short* p) {
    return __builtin_bit_cast(short8, *reinterpret_cast<const uint4*>(p));
}
DEVI short8 pack8(f32x4 lo, f32x4 hi) {
    union { unsigned u[4]; short8 v; } r;
    r.u[0] = cvtpk(lo[0], lo[1]); r.u[1] = cvtpk(lo[2], lo[3]);
    r.u[2] = cvtpk(hi[0], hi[1]); r.u[3] = cvtpk(hi[2], hi[3]);
    return r.v;
}
DEVI f32x4 mfma(short8 a, short8 b, f32x4 c) {
    return __builtin_amdgcn_mfma_f32_16x16x32_bf16(a, b, c, 0, 0, 0);
}
DEVI f32x4 ull2f4(unsigned long long raw) {
    f32x4 r;
#pragma unroll
    for (int e = 0; e < 4; ++e) r[e] = b2f((unsigned short)(raw >> (16 * e)));
    return r;
}
// XOR-swizzled [*][256] bf16 tile: byte ^= (row&7)<<4
DEVI unsigned short* swz(unsigned short* base, int row, int col) {
    int byte = (row * 256 + col) * 2;
    byte ^= (row & 7) << 4;
    return (unsigned short*)((char*)base + byte);
}
DEVI const unsigned short* swzc(const unsigned short* base, int row, int col) {
    int byte = (row * 256 + col) * 2;
    byte ^= (row & 7) << 4;
    return (const unsigned short*)((const char*)base + byte);
}

// ---- weight pre-conversion: f32 -> bf16 ----
__global__ void cvt_w(const float* __restrict__ src, unsigned short* __restrict__ dst, int n) {
    int i = (blockIdx.x * blockDim.x + threadIdx.x) * 8;
    if (i >= n) return;
    f32x4 lo = ld4(src + i), hi = ld4(src + i + 4);
    union { unsigned short s[8]; uint4 v; } r;
#pragma unroll
    for (int e = 0; e < 4; ++e) { r.s[e] = f2b(lo[e]); r.s[4 + e] = f2b(hi[e]); }
    *reinterpret_cast<uint4*>(dst + i) = r.v;
}

// ---- gi precompute, SWAPPED: lane holds (gates gr0+kg*4..+3, batch m) ----
// layout: git[((t*64 + rb)*16 + m)*768 + gate]
__global__ __launch_bounds__(256) void gi_gemm(
    const float* __restrict__ a, const unsigned short* __restrict__ wih,
    unsigned short* __restrict__ git)
{
    const int tid = threadIdx.x;
    const int ww = tid >> 6;
    const int l = tid & 63;
    const int m = l & 15, kg = l >> 4;
    const int b0 = blockIdx.x * 64 + ww * 16;
    const int rb = b0 >> 4;
    const int t = blockIdx.y;

    short8 xb[4];
    {
        const float* xr = a + (size_t)(b0 + m) * T_ * I_ + (size_t)t * I_ + kg * 8;
#pragma unroll
        for (int kt = 0; kt < 4; ++kt)
            xb[kt] = pack8(ld4(xr + kt * 32), ld4(xr + kt * 32 + 4));
    }
#pragma unroll 4
    for (int tl = 0; tl < 48; ++tl) {
        const int gr0 = tl * 16;
        short8 aw[4];
#pragma unroll
        for (int kt = 0; kt < 4; ++kt)
            aw[kt] = ldg8(wih + (size_t)(gr0 + m) * I_ + kt * 32 + kg * 8);
        f32x4 acc = {0.f, 0.f, 0.f, 0.f};
#pragma unroll
        for (int kt = 0; kt < 4; ++kt) acc = mfma(aw[kt], xb[kt], acc);  // A=W!
        const unsigned long long pk =
            (unsigned long long)cvtpk(acc[0], acc[1]) |
            ((unsigned long long)cvtpk(acc[2], acc[3]) << 32);
        __builtin_nontemporal_store(pk, reinterpret_cast<unsigned long long*>(
            git + (((size_t)t * 64 + rb) * 16 + m) * 768 + gr0 + kg * 4));
    }
}

// ---- main kernel: 64 blocks x 1024 threads, swapped-operand MFMAs ----
__global__ __launch_bounds__(1024, 4) void gru_fused16(
    const float* __restrict__ s0,             // [B][H] f32
    const unsigned short* __restrict__ git,   // [T][64][16][768] bf16
    const unsigned short* __restrict__ w_hh,  // [3H][H] bf16
    const unsigned short* __restrict__ w_rw,  // [OUT][H] bf16
    const unsigned short* __restrict__ w_st,  // [H][H] bf16
    float* __restrict__ out_r,                // [T][OUT] f32
    float* __restrict__ out_s)                // [B][T][H] f32
{
    __shared__ unsigned short wst_l[H_ * 256];  // 131072 B, swizzled
    __shared__ unsigned short h16[ROWS * 256];  // 8192 B
    __shared__ unsigned short hn16[ROWS * 256]; // 8192 B   total 147456

    const int tid = threadIdx.x;
    const int w = tid >> 6;       // wave 0..15: gate/state rows w*16..w*16+15
    const int l = tid & 63;
    const int m = l & 15;         // batch row (D col)
    const int kg = l >> 4;
    const int R0 = blockIdx.x * ROWS;
    const int gq = w * 16 + kg * 4;   // this lane's 4-col base (D rows)

    // stage w_state into LDS, swizzled
#pragma unroll
    for (int i = 0; i < 8; ++i) {
        const int idx = (tid + i * 1024) * 8;
        *reinterpret_cast<uint4*>(swz(wst_l, idx >> 8, idx & 255)) =
            *reinterpret_cast<const uint4*>(w_st + idx);
    }
    // init h16
    if (tid < 512) {
        const int pr = tid >> 5, pc = (tid & 31) * 8;
        const float* sp = &s0[(size_t)(R0 + pr) * H_ + pc];
        *reinterpret_cast<uint4*>(swz(h16, pr, pc)) =
            __builtin_bit_cast(uint4, pack8(ld4(sp), ld4(sp + 4)));
    }
    // f32 carry: hreg[v] = h[batch m][col gq+v] (4 consecutive -> one ld4)
    float hreg[4];
    {
        f32x4 h0 = ld4(&s0[(size_t)(R0 + m) * H_ + gq]);
#pragma unroll
        for (int v = 0; v < 4; ++v) hreg[v] = h0[v];
    }
    __syncthreads();

    // A-operand weight rows: gate row w*16+m (same loads as before, new role)
    const unsigned short* pwh = w_hh + (size_t)(w * 16 + m) * H_ + kg * 8;

    // git prefetch (t=0): 3 u64 (r, z, n-input 4-gate groups)
    const size_t gstep = (size_t)64 * 16 * 768;
    const unsigned short* gbase =
        git + ((size_t)blockIdx.x * 16 + m) * 768;
    unsigned long long g0_, g1_, g2_;
    g0_ = __builtin_nontemporal_load(
        reinterpret_cast<const unsigned long long*>(gbase + gq));
    g1_ = __builtin_nontemporal_load(
        reinterpret_cast<const unsigned long long*>(gbase + gq + 256));
    g2_ = __builtin_nontemporal_load(
        reinterpret_cast<const unsigned long long*>(gbase + gq + 512));

    for (int t = 0; t < T_; ++t) {
        // ---- phase 1: gate GEMM, A = weights, B = h ----
        f32x4 ar  = ull2f4(g0_);
        f32x4 az  = ull2f4(g1_);
        f32x4 ani = ull2f4(g2_);
        f32x4 anh = {0.f, 0.f, 0.f, 0.f};

        short8 ha[8];
#pragma unroll
        for (int kt = 0; kt < 8; ++kt)
            ha[kt] = ldg8(swzc(h16, m, kt * 32 + kg * 8));
#pragma unroll
        for (int kt = 0; kt < 8; ++kt)
            ar  = mfma(ldg8(pwh + kt * 32),            ha[kt], ar);
#pragma unroll
        for (int kt = 0; kt < 8; ++kt)
            az  = mfma(ldg8(pwh + 256 * H_ + kt * 32), ha[kt], az);
#pragma unroll
        for (int kt = 0; kt < 8; ++kt)
            anh = mfma(ldg8(pwh + 512 * H_ + kt * 32), ha[kt], anh);

        // ---- gates -> h_new: D = (gate gq+v, batch m) -> packed 8B write ----
        {
            float hv[4];
#pragma unroll
            for (int v = 0; v < 4; ++v) {
                const float rg = sigmoid2_(ar[v]);
                const float zg = sigmoid2_(az[v]);
                const float ng = tanh2_(ani[v] + rg * anh[v]);
                hv[v] = (1.f - zg) * ng + zg * hreg[v];
            }
            uint2 pk; pk.x = cvtpk(hv[0], hv[1]); pk.y = cvtpk(hv[2], hv[3]);
            *reinterpret_cast<uint2*>(swz(hn16, m, gq)) = pk;
        }
        __syncthreads();                      // S1: hn16 ready

        // ---- prefetch git(t+1) ----
        {
            const int tn = (t + 1 < T_) ? t + 1 : t;
            const unsigned short* gt = gbase + (size_t)tn * gstep;
            g0_ = __builtin_nontemporal_load(
                reinterpret_cast<const unsigned long long*>(gt + gq));
            g1_ = __builtin_nontemporal_load(
                reinterpret_cast<const unsigned long long*>(gt + gq + 256));
            g2_ = __builtin_nontemporal_load(
                reinterpret_cast<const unsigned long long*>(gt + gq + 512));
        }

        // ---- phase 2: s = sig(hn @ w_state^T), A = wst (LDS), B = hn ----
        short8 na[8];
#pragma unroll
        for (int kt = 0; kt < 8; ++kt)
            na[kt] = ldg8(swzc(hn16, m, kt * 32 + kg * 8));
        f32x4 sa = {0.f, 0.f, 0.f, 0.f};
#pragma unroll
        for (int kt = 0; kt < 8; ++kt)
            sa = mfma(ldg8(swzc(wst_l, w * 16 + m, kt * 32 + kg * 8)), na[kt], sa);
        {
            float sv[4];
#pragma unroll
            for (int v = 0; v < 4; ++v) {
                sv[v] = sigmoid2_(sa[v]);
                hreg[v] = sv[v];
            }
            uint2 pk; pk.x = cvtpk(sv[0], sv[1]); pk.y = cvtpk(sv[2], sv[3]);
            *reinterpret_cast<uint2*>(swz(h16, m, gq)) = pk;
            f32x4 o4 = {sv[0], sv[1], sv[2], sv[3]};
            __builtin_nontemporal_store(o4, reinterpret_cast<f32x4*>(
                &out_s[((size_t)(R0 + m) * T_ + t) * H_ + gq]));
        }
        if (blockIdx.x == 0 && w < 4) {       // r_t: A = w_rw rows w*16+m
            f32x4 accr = {0.f, 0.f, 0.f, 0.f};
            const unsigned short* p = w_rw + (size_t)(w * 16 + m) * H_ + kg * 8;
#pragma unroll
            for (int kt = 0; kt < 8; ++kt)
                accr = mfma(ldg8(p + kt * 32), na[kt], accr);
            if (m == 0) {                     // batch row 0 = D col 0
                f32x4 o4 = {sigmoid2_(accr[0]), sigmoid2_(accr[1]),
                            sigmoid2_(accr[2]), sigmoid2_(accr[3])};
                *reinterpret_cast<f32x4*>(&out_r[t * OUT_ + w * 16 + kg * 4]) = o4;
            }
        }
        __syncthreads();                      // S2: h16 ready for t+1
    }
}

// ---- fallback (ws too small): r16 streaming kernel, 64 blocks ----
__global__ __launch_bounds__(512, 1) void gru_fallback(
    const float* __restrict__ s0, const float* __restrict__ a,
    const unsigned short* __restrict__ w_ih, const unsigned short* __restrict__ w_hh,
    const unsigned short* __restrict__ w_rw, const unsigned short* __restrict__ w_st,
    float* __restrict__ out_r, float* __restrict__ out_s)
{
    __shared__ unsigned short wst_l[H_ * 256];
    __shared__ unsigned short h16a[16 * 256];
    __shared__ unsigned short hn16a[16 * 256];
    const int tid = threadIdx.x;
    const int w = tid >> 6, l = tid & 63, m = l & 15, kg = l >> 4;
    const int R0 = blockIdx.x * 16;
    const int g0 = (2 * w + 0) * 16 + m, g1 = (2 * w + 1) * 16 + m;
#pragma unroll
    for (int i = 0; i < 16; ++i) {
        const int idx = (tid + i * 512) * 8;
        *reinterpret_cast<uint4*>(swz(wst_l, idx >> 8, idx & 255)) =
            *reinterpret_cast<const uint4*>(w_st + idx);
    }
    {
        const int pr = tid >> 5, pc = (tid & 31) * 8;
        const float* sp = &s0[(size_t)(R0 + pr) * H_ + pc];
        *reinterpret_cast<uint4*>(swz(h16a, pr, pc)) =
            __builtin_bit_cast(uint4, pack8(ld4(sp), ld4(sp + 4)));
    }
    float hreg0[4], hreg1[4];
#pragma unroll
    for (int v = 0; v < 4; ++v) {
        hreg0[v] = s0[(size_t)(R0 + kg * 4 + v) * H_ + g0];
        hreg1[v] = s0[(size_t)(R0 + kg * 4 + v) * H_ + g1];
    }
    __syncthreads();
    for (int t = 0; t < T_; ++t) {
        short8 ha[8];
#pragma unroll
        for (int kt = 0; kt < 8; ++kt) ha[kt] = ldg8(swzc(h16a, m, kt * 32 + kg * 8));
        f32x4 ar0 = {0,0,0,0}, az0 = {0,0,0,0}, ani0 = {0,0,0,0};
        f32x4 ar1 = {0,0,0,0}, az1 = {0,0,0,0}, ani1 = {0,0,0,0};
        short8 xa[4];
        const float* xr = a + ((size_t)(R0 + m) * T_ + t) * I_ + kg * 8;
#pragma unroll
        for (int kt = 0; kt < 4; ++kt)
            xa[kt] = pack8(ld4(xr + kt * 32), ld4(xr + kt * 32 + 4));
        const unsigned short* p0 = w_ih + (size_t)g0 * I_ + kg * 8;
        const unsigned short* p1 = w_ih + (size_t)g1 * I_ + kg * 8;
#pragma unroll
        for (int kt = 0; kt < 4; ++kt) {
            ar0  = mfma(xa[kt], ldg8(p0 + kt * 32),            ar0);
            az0  = mfma(xa[kt], ldg8(p0 + 256 * I_ + kt * 32), az0);
            ani0 = mfma(xa[kt], ldg8(p0 + 512 * I_ + kt * 32), ani0);
            ar1  = mfma(xa[kt], ldg8(p1 + kt * 32),            ar1);
            az1  = mfma(xa[kt], ldg8(p1 + 256 * I_ + kt * 32), az1);
            ani1 = mfma(xa[kt], ldg8(p1 + 512 * I_ + kt * 32), ani1);
        }
        f32x4 anh0 = {0,0,0,0}, anh1 = {0,0,0,0};
        const unsigned short* q0 = w_hh + (size_t)g0 * H_ + kg * 8;
        const unsigned short* q1 = w_hh + (size_t)g1 * H_ + kg * 8;
#pragma unroll
        for (int kt = 0; kt < 8; ++kt) {
            ar0  = mfma(ha[kt], ldg8(q0 + kt * 32),            ar0);
            az0  = mfma(ha[kt], ldg8(q0 + 256 * H_ + kt * 32), az0);
            anh0 = mfma(ha[kt], ldg8(q0 + 512 * H_ + kt * 32), anh0);
            ar1  = mfma(ha[kt], ldg8(q1 + kt * 32),            ar1);
            az1  = mfma(ha[kt], ldg8(q1 + 256 * H_ + kt * 32), az1);
            anh1 = mfma(ha[kt], ldg8(q1 + 512 * H_ + kt * 32), anh1);
        }
#pragma unroll
        for (int v = 0; v < 4; ++v) {
            const int row = kg * 4 + v;
            float rg = sigmoid2_(ar0[v]), zg = sigmoid2_(az0[v]);
            float ng = tanh2_(ani0[v] + rg * anh0[v]);
            *swz(hn16a, row, g0) = f2b((1.f - zg) * ng + zg * hreg0[v]);
            rg = sigmoid2_(ar1[v]); zg = sigmoid2_(az1[v]);
            ng = tanh2_(ani1[v] + rg * anh1[v]);
            *swz(hn16a, row, g1) = f2b((1.f - zg) * ng + zg * hreg1[v]);
        }
        __syncthreads();
        short8 na[8];
#pragma unroll
        for (int kt = 0; kt < 8; ++kt) na[kt] = ldg8(swzc(hn16a, m, kt * 32 + kg * 8));
        f32x4 sa0 = {0,0,0,0}, sa1 = {0,0,0,0};
#pragma unroll
        for (int kt = 0; kt < 8; ++kt) {
            sa0 = mfma(na[kt], ldg8(swzc(wst_l, g0, kt * 32 + kg * 8)), sa0);
            sa1 = mfma(na[kt], ldg8(swzc(wst_l, g1, kt * 32 + kg * 8)), sa1);
        }
#pragma unroll
        for (int v = 0; v < 4; ++v) {
            const int row = kg * 4 + v;
            const float u0 = sigmoid2_(sa0[v]), u1 = sigmoid2_(sa1[v]);
            hreg0[v] = u0; hreg1[v] = u1;
            *swz(h16a, row, g0) = f2b(u0);
            *swz(h16a, row, g1) = f2b(u1);
            float* dst = &out_s[((size_t)(R0 + row) * T_ + t) * H_];
            dst[g0] = u0; dst[g1] = u1;
        }
        if (blockIdx.x == 0 && w < 4) {
            const int o = w * 16 + m;
            f32x4 accr = {0,0,0,0};
            const unsigned short* pw = w_rw + (size_t)o * H_ + kg * 8;
#pragma unroll
            for (int kt = 0; kt < 8; ++kt) accr = mfma(na[kt], ldg8(pw + kt * 32), accr);
            if (kg == 0) out_r[t * OUT_ + o] = sigmoid2_(accr[0]);
        }
        __syncthreads();
    }
}

extern "C" void kernel_launch(void* const* d_in, const int* in_sizes, int n_in,
                              void* d_out, int out_size, void* d_ws, size_t ws_size,
                              hipStream_t stream) {
    const float* s0  = (const float*)d_in[0];
    const float* a   = (const float*)d_in[1];
    const float* wih = (const float*)d_in[2];
    const float* whh = (const float*)d_in[3];
    const float* wrw = (const float*)d_in[4];
    const float* wst = (const float*)d_in[5];

    const size_t git_e  = (size_t)T_ * 64 * 16 * 768;     // 100,663,296 u16
    const size_t wtot_e = 98304 + 196608 + 16384 + 65536; // 376,832 u16
    const bool pregi = ws_size >= (git_e + wtot_e) * 2;

    unsigned short* ws16  = (unsigned short*)d_ws;
    unsigned short* git   = ws16;
    unsigned short* wih16 = ws16 + (pregi ? git_e : 0);
    unsigned short* whh16 = wih16 + 98304;
    unsigned short* wrw16 = whh16 + 196608;
    unsigned short* wst16 = wrw16 + 16384;

    cvt_w<<<98304  / (256 * 8), 256, 0, stream>>>(wih, wih16, 98304);
    cvt_w<<<196608 / (256 * 8), 256, 0, stream>>>(whh, whh16, 196608);
    cvt_w<<<16384  / (256 * 8), 256, 0, stream>>>(wrw, wrw16, 16384);
    cvt_w<<<65536  / (256 * 8), 256, 0, stream>>>(wst, wst16, 65536);

    float* out = (float*)d_out;
    if (pregi) {
        gi_gemm<<<dim3(16, T_), 256, 0, stream>>>(a, wih16, git);
        gru_fused16<<<NBLK, 1024, 0, stream>>>(s0, git, whh16, wrw16, wst16,
                                               out, out + (size_t)T_ * OUT_);
    } else {
        gru_fallback<<<64, 512, 0, stream>>>(s0, a, wih16, whh16, wrw16, wst16,
                                             out, out + (size_t)T_ * OUT_);
    }
}

// Round 18
// 1033.969 us; speedup vs baseline: 14.7324x; 1.2571x over previous
//
#include <hip/hip_runtime.h>

// GRU recurrence (round 18).
// r17: 1110us; cost = w_hh stream (6K cyc/step/CU, per-CU invariant) + LDS
// (3K + 1.7K conflicts) + latency. Two levers:
//  (1) tile-major LDS layouts (h/hn: [kt][kg][m][8]; wst: [rt][kt][kg][rm][8])
//      -> provably conflict-free b128 reads (contiguous 1KB bursts) and 8B
//      writes; XOR swizzle removed.
//  (2) 128 blocks x ROWS=8: per-CU stream unchanged but batch-proportional
//      work halves and 2x CUs run in parallel (L2 aggregate 3.2K cyc < 6K
//      per-CU floor; weights shared + L2-resident, git nt-streamed).

typedef __attribute__((ext_vector_type(8))) short short8;
typedef __attribute__((ext_vector_type(4))) float f32x4;

constexpr int B_ = 1024, T_ = 128, I_ = 128, H_ = 256, OUT_ = 64;
constexpr int ROWS = 8;
constexpr int NBLK = B_ / ROWS;  // 128

#define DEVI __device__ __forceinline__

DEVI unsigned short f2b(float f) {
    unsigned u = __builtin_bit_cast(unsigned, f);
    u += 0x7fffu + ((u >> 16) & 1u);
    return (unsigned short)(u >> 16);
}
DEVI float b2f(unsigned short s) {
    unsigned u = ((unsigned)s) << 16;
    return __builtin_bit_cast(float, u);
}
DEVI unsigned cvtpk(float lo, float hi) {
    unsigned r;
    asm("v_cvt_pk_bf16_f32 %0, %1, %2" : "=v"(r) : "v"(lo), "v"(hi));
    return r;
}
DEVI float sigmoid2_(float x) {
    float e = __builtin_amdgcn_exp2f(-1.44269504f * x);
    return __builtin_amdgcn_rcpf(1.f + e);
}
DEVI float tanh2_(float x) {
    float e = __builtin_amdgcn_exp2f(2.88539009f * x);
    return (e - 1.f) * __builtin_amdgcn_rcpf(e + 1.f);
}

DEVI f32x4 ld4(const void* p) { return *reinterpret_cast<const f32x4*>(p); }
DEVI short8 ldg8(const unsigned short* p) {
    return __builtin_bit_cast(short8, *reinterpret_cast<const uint4*>(p));
}
DEVI short8 pack8(f32x4 lo, f32x4 hi) {
    union { unsigned u[4]; short8 v; } r;
    r.u[0] = cvtpk(lo[0], lo[1]); r.u[1] = cvtpk(lo[2], lo[3]);
    r.u[2] = cvtpk(hi[0], hi[1]); r.u[3] = cvtpk(hi[2], hi[3]);
    return r.v;
}
DEVI f32x4 mfma(short8 a, short8 b, f32x4 c) {
    return __builtin_amdgcn_mfma_f32_16x16x32_bf16(a, b, c, 0, 0, 0);
}
DEVI f32x4 ull2f4(unsigned long long raw) {
    f32x4 r;
#pragma unroll
    for (int e = 0; e < 4; ++e) r[e] = b2f((unsigned short)(raw >> (16 * e)));
    return r;
}
// tile-major offsets (elem units)
DEVI int hoff(int b, int c) {        // h/hn: b 0..7, c 0..255
    return (c >> 5) * 256 + ((c >> 3) & 3) * 64 + b * 8 + (c & 7);
}
DEVI int woff(int r, int c) {        // wst: r 0..255, c 0..255
    return ((r >> 4) * 8 + (c >> 5)) * 512 + ((c >> 3) & 3) * 128 + (r & 15) * 8 + (c & 7);
}
// legacy swizzle (fallback kernel only)
DEVI unsigned short* swz(unsigned short* base, int row, int col) {
    int byte = (row * 256 + col) * 2;
    byte ^= (row & 7) << 4;
    return (unsigned short*)((char*)base + byte);
}
DEVI const unsigned short* swzc(const unsigned short* base, int row, int col) {
    int byte = (row * 256 + col) * 2;
    byte ^= (row & 7) << 4;
    return (const unsigned short*)((const char*)base + byte);
}

// ---- weight pre-conversion: f32 -> bf16 ----
__global__ void cvt_w(const float* __restrict__ src, unsigned short* __restrict__ dst, int n) {
    int i = (blockIdx.x * blockDim.x + threadIdx.x) * 8;
    if (i >= n) return;
    f32x4 lo = ld4(src + i), hi = ld4(src + i + 4);
    union { unsigned short s[8]; uint4 v; } r;
#pragma unroll
    for (int e = 0; e < 4; ++e) { r.s[e] = f2b(lo[e]); r.s[4 + e] = f2b(hi[e]); }
    *reinterpret_cast<uint4*>(dst + i) = r.v;
}

// ---- gi precompute: git[((t*128 + rb)*8 + b&7)*768 + gate], swapped D ----
__global__ __launch_bounds__(256) void gi_gemm(
    const float* __restrict__ a, const unsigned short* __restrict__ wih,
    unsigned short* __restrict__ git)
{
    const int tid = threadIdx.x;
    const int ww = tid >> 6;
    const int l = tid & 63;
    const int m = l & 15, kg = l >> 4;
    const int b0 = blockIdx.x * 64 + ww * 16;
    const int t = blockIdx.y;

    short8 xb[4];
    {
        const float* xr = a + (size_t)(b0 + m) * T_ * I_ + (size_t)t * I_ + kg * 8;
#pragma unroll
        for (int kt = 0; kt < 4; ++kt)
            xb[kt] = pack8(ld4(xr + kt * 32), ld4(xr + kt * 32 + 4));
    }
    const int b = b0 + m;
    unsigned short* gdst = git + (((size_t)t * 128 + (b >> 3)) * 8 + (b & 7)) * 768;
#pragma unroll 4
    for (int tl = 0; tl < 48; ++tl) {
        const int gr0 = tl * 16;
        short8 aw[4];
#pragma unroll
        for (int kt = 0; kt < 4; ++kt)
            aw[kt] = ldg8(wih + (size_t)(gr0 + m) * I_ + kt * 32 + kg * 8);
        f32x4 acc = {0.f, 0.f, 0.f, 0.f};
#pragma unroll
        for (int kt = 0; kt < 4; ++kt) acc = mfma(aw[kt], xb[kt], acc);
        const unsigned long long pk =
            (unsigned long long)cvtpk(acc[0], acc[1]) |
            ((unsigned long long)cvtpk(acc[2], acc[3]) << 32);
        __builtin_nontemporal_store(pk, reinterpret_cast<unsigned long long*>(
            gdst + gr0 + kg * 4));
    }
}

// ---- main kernel: 128 blocks x 1024 threads, ROWS=8, tile-major LDS ----
__global__ __launch_bounds__(1024, 4) void gru_fused8(
    const float* __restrict__ s0,             // [B][H] f32
    const unsigned short* __restrict__ git,   // [T][128][8][768] bf16
    const unsigned short* __restrict__ w_hh,  // [3H][H] bf16
    const unsigned short* __restrict__ w_rw,  // [OUT][H] bf16
    const unsigned short* __restrict__ w_st,  // [H][H] bf16
    float* __restrict__ out_r,                // [T][OUT] f32
    float* __restrict__ out_s)                // [B][T][H] f32
{
    __shared__ unsigned short wst_l[H_ * 256];  // 131072 B, tile-major
    __shared__ unsigned short h16[ROWS * 256];  // 4096 B, tile-major
    __shared__ unsigned short hn16[ROWS * 256]; // 4096 B   total 139264

    const int tid = threadIdx.x;
    const int w = tid >> 6;       // wave 0..15: gate/state rows w*16..+15
    const int l = tid & 63;
    const int m = l & 15;         // batch (D col); valid m<8, m>=8 mirrors
    const int kg = l >> 4;
    const int R0 = blockIdx.x * ROWS;
    const int gq = w * 16 + kg * 4;   // this lane's 4 D-rows (gate/state cols)

    // stage w_state into LDS, tile-major (65536 elems; 8 uint4 per thread)
#pragma unroll
    for (int i = 0; i < 8; ++i) {
        const int idx = (tid + i * 1024) * 8;
        *reinterpret_cast<uint4*>(&wst_l[woff(idx >> 8, idx & 255)]) =
            *reinterpret_cast<const uint4*>(w_st + idx);
    }
    // init h16 (2048 elems, 256 threads x 8)
    if (tid < 256) {
        const int b = tid >> 5, c0 = (tid & 31) * 8;
        const float* sp = &s0[(size_t)(R0 + b) * H_ + c0];
        *reinterpret_cast<uint4*>(&h16[hoff(b, c0)]) =
            __builtin_bit_cast(uint4, pack8(ld4(sp), ld4(sp + 4)));
    }
    // f32 carry: lane m<8 holds s[batch m][gq..gq+3]
    float hreg[4] = {0.f, 0.f, 0.f, 0.f};
    if (m < 8) {
        f32x4 h0 = ld4(&s0[(size_t)(R0 + m) * H_ + gq]);
#pragma unroll
        for (int v = 0; v < 4; ++v) hreg[v] = h0[v];
    }
    __syncthreads();

    const unsigned short* pwh = w_hh + (size_t)(w * 16 + m) * H_ + kg * 8;

    // git prefetch (t=0): 3 u64 (r,z,ni) for lane m<8
    const size_t gstep = (size_t)128 * 8 * 768;
    const unsigned short* gbase =
        git + ((size_t)blockIdx.x * 8 + (m & 7)) * 768;
    unsigned long long g0_ = 0, g1_ = 0, g2_ = 0;
    if (m < 8) {
        g0_ = __builtin_nontemporal_load(
            reinterpret_cast<const unsigned long long*>(gbase + gq));
        g1_ = __builtin_nontemporal_load(
            reinterpret_cast<const unsigned long long*>(gbase + gq + 256));
        g2_ = __builtin_nontemporal_load(
            reinterpret_cast<const unsigned long long*>(gbase + gq + 512));
    }

    for (int t = 0; t < T_; ++t) {
        // ---- phase 1: gate GEMM, A = w_hh rows, B = h (tile-major LDS) ----
        f32x4 ar  = ull2f4(g0_);
        f32x4 az  = ull2f4(g1_);
        f32x4 ani = ull2f4(g2_);
        f32x4 anh = {0.f, 0.f, 0.f, 0.f};

        short8 ha[8];
#pragma unroll
        for (int kt = 0; kt < 8; ++kt)
            ha[kt] = ldg8(&h16[kt * 256 + kg * 64 + (m & 7) * 8]);
#pragma unroll
        for (int kt = 0; kt < 8; ++kt)
            ar  = mfma(ldg8(pwh + kt * 32),            ha[kt], ar);
#pragma unroll
        for (int kt = 0; kt < 8; ++kt)
            az  = mfma(ldg8(pwh + 256 * H_ + kt * 32), ha[kt], az);
#pragma unroll
        for (int kt = 0; kt < 8; ++kt)
            anh = mfma(ldg8(pwh + 512 * H_ + kt * 32), ha[kt], anh);

        // ---- gates -> h_new (lane m<8 writes 8B) ----
        if (m < 8) {
            float hv[4];
#pragma unroll
            for (int v = 0; v < 4; ++v) {
                const float rg = sigmoid2_(ar[v]);
                const float zg = sigmoid2_(az[v]);
                const float ng = tanh2_(ani[v] + rg * anh[v]);
                hv[v] = (1.f - zg) * ng + zg * hreg[v];
            }
            uint2 pk; pk.x = cvtpk(hv[0], hv[1]); pk.y = cvtpk(hv[2], hv[3]);
            *reinterpret_cast<uint2*>(&hn16[hoff(m, gq)]) = pk;
        }
        __syncthreads();                      // S1: hn16 ready

        // ---- prefetch git(t+1) ----
        if (m < 8) {
            const int tn = (t + 1 < T_) ? t + 1 : t;
            const unsigned short* gt = gbase + (size_t)tn * gstep;
            g0_ = __builtin_nontemporal_load(
                reinterpret_cast<const unsigned long long*>(gt + gq));
            g1_ = __builtin_nontemporal_load(
                reinterpret_cast<const unsigned long long*>(gt + gq + 256));
            g2_ = __builtin_nontemporal_load(
                reinterpret_cast<const unsigned long long*>(gt + gq + 512));
        }

        // ---- phase 2: s = sig(hn @ w_state^T), A = wst (LDS), B = hn ----
        short8 na[8];
#pragma unroll
        for (int kt = 0; kt < 8; ++kt)
            na[kt] = ldg8(&hn16[kt * 256 + kg * 64 + (m & 7) * 8]);
        f32x4 sa = {0.f, 0.f, 0.f, 0.f};
#pragma unroll
        for (int kt = 0; kt < 8; ++kt)
            sa = mfma(ldg8(&wst_l[(w * 8 + kt) * 512 + kg * 128 + m * 8]),
                      na[kt], sa);
        if (m < 8) {
            float sv[4];
#pragma unroll
            for (int v = 0; v < 4; ++v) {
                sv[v] = sigmoid2_(sa[v]);
                hreg[v] = sv[v];
            }
            uint2 pk; pk.x = cvtpk(sv[0], sv[1]); pk.y = cvtpk(sv[2], sv[3]);
            *reinterpret_cast<uint2*>(&h16[hoff(m, gq)]) = pk;
            f32x4 o4 = {sv[0], sv[1], sv[2], sv[3]};
            __builtin_nontemporal_store(o4, reinterpret_cast<f32x4*>(
                &out_s[((size_t)(R0 + m) * T_ + t) * H_ + gq]));
        }
        if (blockIdx.x == 0 && w < 4) {       // r_t: A = w_rw rows w*16+m
            f32x4 accr = {0.f, 0.f, 0.f, 0.f};
            const unsigned short* p = w_rw + (size_t)(w * 16 + m) * H_ + kg * 8;
#pragma unroll
            for (int kt = 0; kt < 8; ++kt)
                accr = mfma(ldg8(p + kt * 32), na[kt], accr);
            if (m == 0) {                     // batch row 0 = D col 0
                f32x4 o4 = {sigmoid2_(accr[0]), sigmoid2_(accr[1]),
                            sigmoid2_(accr[2]), sigmoid2_(accr[3])};
                *reinterpret_cast<f32x4*>(&out_r[t * OUT_ + w * 16 + kg * 4]) = o4;
            }
        }
        __syncthreads();                      // S2: h16 ready for t+1
    }
}

// ---- fallback (ws too small): r17 streaming kernel, 64 blocks ----
__global__ __launch_bounds__(512, 1) void gru_fallback(
    const float* __restrict__ s0, const float* __restrict__ a,
    const unsigned short* __restrict__ w_ih, const unsigned short* __restrict__ w_hh,
    const unsigned short* __restrict__ w_rw, const unsigned short* __restrict__ w_st,
    float* __restrict__ out_r, float* __restrict__ out_s)
{
    __shared__ unsigned short wst_l[H_ * 256];
    __shared__ unsigned short h16a[16 * 256];
    __shared__ unsigned short hn16a[16 * 256];
    const int tid = threadIdx.x;
    const int w = tid >> 6, l = tid & 63, m = l & 15, kg = l >> 4;
    const int R0 = blockIdx.x * 16;
    const int g0 = (2 * w + 0) * 16 + m, g1 = (2 * w + 1) * 16 + m;
#pragma unroll
    for (int i = 0; i < 16; ++i) {
        const int idx = (tid + i * 512) * 8;
        *reinterpret_cast<uint4*>(swz(wst_l, idx >> 8, idx & 255)) =
            *reinterpret_cast<const uint4*>(w_st + idx);
    }
    {
        const int pr = tid >> 5, pc = (tid & 31) * 8;
        const float* sp = &s0[(size_t)(R0 + pr) * H_ + pc];
        *reinterpret_cast<uint4*>(swz(h16a, pr, pc)) =
            __builtin_bit_cast(uint4, pack8(ld4(sp), ld4(sp + 4)));
    }
    float hreg0[4], hreg1[4];
#pragma unroll
    for (int v = 0; v < 4; ++v) {
        hreg0[v] = s0[(size_t)(R0 + kg * 4 + v) * H_ + g0];
        hreg1[v] = s0[(size_t)(R0 + kg * 4 + v) * H_ + g1];
    }
    __syncthreads();
    for (int t = 0; t < T_; ++t) {
        short8 ha[8];
#pragma unroll
        for (int kt = 0; kt < 8; ++kt) ha[kt] = ldg8(swzc(h16a, m, kt * 32 + kg * 8));
        f32x4 ar0 = {0,0,0,0}, az0 = {0,0,0,0}, ani0 = {0,0,0,0};
        f32x4 ar1 = {0,0,0,0}, az1 = {0,0,0,0}, ani1 = {0,0,0,0};
        short8 xa[4];
        const float* xr = a + ((size_t)(R0 + m) * T_ + t) * I_ + kg * 8;
#pragma unroll
        for (int kt = 0; kt < 4; ++kt)
            xa[kt] = pack8(ld4(xr + kt * 32), ld4(xr + kt * 32 + 4));
        const unsigned short* p0 = w_ih + (size_t)g0 * I_ + kg * 8;
        const unsigned short* p1 = w_ih + (size_t)g1 * I_ + kg * 8;
#pragma unroll
        for (int kt = 0; kt < 4; ++kt) {
            ar0  = mfma(xa[kt], ldg8(p0 + kt * 32),            ar0);
            az0  = mfma(xa[kt], ldg8(p0 + 256 * I_ + kt * 32), az0);
            ani0 = mfma(xa[kt], ldg8(p0 + 512 * I_ + kt * 32), ani0);
            ar1  = mfma(xa[kt], ldg8(p1 + kt * 32),            ar1);
            az1  = mfma(xa[kt], ldg8(p1 + 256 * I_ + kt * 32), az1);
            ani1 = mfma(xa[kt], ldg8(p1 + 512 * I_ + kt * 32), ani1);
        }
        f32x4 anh0 = {0,0,0,0}, anh1 = {0,0,0,0};
        const unsigned short* q0 = w_hh + (size_t)g0 * H_ + kg * 8;
        const unsigned short* q1 = w_hh + (size_t)g1 * H_ + kg * 8;
#pragma unroll
        for (int kt = 0; kt < 8; ++kt) {
            ar0  = mfma(ha[kt], ldg8(q0 + kt * 32),            ar0);
            az0  = mfma(ha[kt], ldg8(q0 + 256 * H_ + kt * 32), az0);
            anh0 = mfma(ha[kt], ldg8(q0 + 512 * H_ + kt * 32), anh0);
            ar1  = mfma(ha[kt], ldg8(q1 + kt * 32),            ar1);
            az1  = mfma(ha[kt], ldg8(q1 + 256 * H_ + kt * 32), az1);
            anh1 = mfma(ha[kt], ldg8(q1 + 512 * H_ + kt * 32), anh1);
        }
#pragma unroll
        for (int v = 0; v < 4; ++v) {
            const int row = kg * 4 + v;
            float rg = sigmoid2_(ar0[v]), zg = sigmoid2_(az0[v]);
            float ng = tanh2_(ani0[v] + rg * anh0[v]);
            *swz(hn16a, row, g0) = f2b((1.f - zg) * ng + zg * hreg0[v]);
            rg = sigmoid2_(ar1[v]); zg = sigmoid2_(az1[v]);
            ng = tanh2_(ani1[v] + rg * anh1[v]);
            *swz(hn16a, row, g1) = f2b((1.f - zg) * ng + zg * hreg1[v]);
        }
        __syncthreads();
        short8 na[8];
#pragma unroll
        for (int kt = 0; kt < 8; ++kt) na[kt] = ldg8(swzc(hn16a, m, kt * 32 + kg * 8));
        f32x4 sa0 = {0,0,0,0}, sa1 = {0,0,0,0};
#pragma unroll
        for (int kt = 0; kt < 8; ++kt) {
            sa0 = mfma(na[kt], ldg8(swzc(wst_l, g0, kt * 32 + kg * 8)), sa0);
            sa1 = mfma(na[kt], ldg8(swzc(wst_l, g1, kt * 32 + kg * 8)), sa1);
        }
#pragma unroll
        for (int v = 0; v < 4; ++v) {
            const int row = kg * 4 + v;
            const float u0 = sigmoid2_(sa0[v]), u1 = sigmoid2_(sa1[v]);
            hreg0[v] = u0; hreg1[v] = u1;
            *swz(h16a, row, g0) = f2b(u0);
            *swz(h16a, row, g1) = f2b(u1);
            float* dst = &out_s[((size_t)(R0 + row) * T_ + t) * H_];
            dst[g0] = u0; dst[g1] = u1;
        }
        if (blockIdx.x == 0 && w < 4) {
            const int o = w * 16 + m;
            f32x4 accr = {0,0,0,0};
            const unsigned short* pw = w_rw + (size_t)o * H_ + kg * 8;
#pragma unroll
            for (int kt = 0; kt < 8; ++kt) accr = mfma(na[kt], ldg8(pw + kt * 32), accr);
            if (kg == 0) out_r[t * OUT_ + o] = sigmoid2_(accr[0]);
        }
        __syncthreads();
    }
}

extern "C" void kernel_launch(void* const* d_in, const int* in_sizes, int n_in,
                              void* d_out, int out_size, void* d_ws, size_t ws_size,
                              hipStream_t stream) {
    const float* s0  = (const float*)d_in[0];
    const float* a   = (const float*)d_in[1];
    const float* wih = (const float*)d_in[2];
    const float* whh = (const float*)d_in[3];
    const float* wrw = (const float*)d_in[4];
    const float* wst = (const float*)d_in[5];

    const size_t git_e  = (size_t)T_ * 128 * 8 * 768;     // 100,663,296 u16
    const size_t wtot_e = 98304 + 196608 + 16384 + 65536; // 376,832 u16
    const bool pregi = ws_size >= (git_e + wtot_e) * 2;

    unsigned short* ws16  = (unsigned short*)d_ws;
    unsigned short* git   = ws16;
    unsigned short* wih16 = ws16 + (pregi ? git_e : 0);
    unsigned short* whh16 = wih16 + 98304;
    unsigned short* wrw16 = whh16 + 196608;
    unsigned short* wst16 = wrw16 + 16384;

    cvt_w<<<98304  / (256 * 8), 256, 0, stream>>>(wih, wih16, 98304);
    cvt_w<<<196608 / (256 * 8), 256, 0, stream>>>(whh, whh16, 196608);
    cvt_w<<<16384  / (256 * 8), 256, 0, stream>>>(wrw, wrw16, 16384);
    cvt_w<<<65536  / (256 * 8), 256, 0, stream>>>(wst, wst16, 65536);

    float* out = (float*)d_out;
    if (pregi) {
        gi_gemm<<<dim3(16, T_), 256, 0, stream>>>(a, wih16, git);
        gru_fused8<<<NBLK, 1024, 0, stream>>>(s0, git, whh16, wrw16, wst16,
                                              out, out + (size_t)T_ * OUT_);
    } else {
        gru_fallback<<<64, 512, 0, stream>>>(s0, a, wih16, whh16, wrw16, wst16,
                                             out, out + (size_t)T_ * OUT_);
    }
}